// Round 4
// baseline (374.679 us; speedup 1.0000x reference)
//
#include <hip/hip_runtime.h>
#include <math.h>

// B=2, S=64, C=64, NH=8, H=W=32, M1=M2=16 (256 modes), mode m=p*16+q.
// lambda/mu: m==0 -> 1 (imag zeroed), m%16==0 -> 0.5, else 2.

#define PI_F 3.14159265358979323846f

typedef _Float16 f16;
typedef f16 f16x8 __attribute__((ext_vector_type(8)));
typedef f16 f16x4 __attribute__((ext_vector_type(4)));
typedef float f32x4 __attribute__((ext_vector_type(4)));

#define MFMA(a, b, c) __builtin_amdgcn_mfma_f32_16x16x32_f16(a, b, c, 0, 0, 0)

// byte offset of a 16B slot in an 8KB [64 rows][64 f16] plane, XOR-swizzled
__device__ __forceinline__ int swz128(int row, int slot) {
  return (row << 7) + (((slot) ^ (row & 7)) << 4);
}
// byte offset of one f16 element (same swizzle)
__device__ __forceinline__ int swzel(int row, int col) {
  return (row << 7) + ((((col) >> 3) ^ (row & 7)) << 4) + (((col) & 7) << 1);
}

// ---------------- K1: forward DFT -> fp16 re/im planes [b][m][s*64+i] ------
__global__ __launch_bounds__(256) void k_dft(const float* __restrict__ seq,
                                             f16* __restrict__ Xr,
                                             f16* __restrict__ Xi) {
  __shared__ float fld[32][33];
  __shared__ float2 tb[32][17];
  __shared__ float2 tw[32];
  int f = blockIdx.x;
  int tid = threadIdx.x;
  if (tid < 32) {
    float a = (2.0f * PI_F / 32.0f) * (float)tid;
    tw[tid] = make_float2(cosf(a), sinf(a));
  }
  const float4* s4 = (const float4*)(seq + (size_t)f * 1024);
  float4 v = s4[tid];
  int x0 = tid >> 3, y0 = (tid & 7) * 4;
  fld[x0][y0 + 0] = v.x; fld[x0][y0 + 1] = v.y;
  fld[x0][y0 + 2] = v.z; fld[x0][y0 + 3] = v.w;
  __syncthreads();
  for (int o = tid; o < 512; o += 256) {
    int x = o >> 4, q = o & 15;
    float re = 0.f, im = 0.f;
#pragma unroll
    for (int y = 0; y < 32; ++y) {
      float val = fld[x][y];
      float2 w = tw[(q * y) & 31];
      re = fmaf(val, w.x, re);
      im = fmaf(val, -w.y, im);
    }
    tb[x][q] = make_float2(re, im);
  }
  __syncthreads();
  int p = tid >> 4, q = tid & 15;
  float re = 0.f, im = 0.f;
#pragma unroll
  for (int x = 0; x < 32; ++x) {
    float2 t = tb[x][q];
    float2 w = tw[(p * x) & 31];
    re += w.x * t.x + w.y * t.y;
    im += w.x * t.y - w.y * t.x;
  }
  int b = f >> 12;
  int si = f & 4095;
  size_t o = (size_t)(b * 256 + tid) * 4096 + si;
  Xr[o] = (f16)re;
  Xi[o] = (f16)im;
}

// ---------------- K-repack (single launch, all 4 tensors) ------------------
// q/k/v: raw [i(64)][hd(512)][m], planes [m][hd*64+i]
// wo:    raw [hd(512)][c(64)][m], planes [m][c*512+hd]
__global__ __launch_bounds__(256) void k_repack_all(
    const float2* __restrict__ wq, const float2* __restrict__ wk,
    const float2* __restrict__ wv, const float2* __restrict__ wo,
    f16* __restrict__ Pqr, f16* __restrict__ Pqi, f16* __restrict__ Pkr,
    f16* __restrict__ Pki, f16* __restrict__ Pvr, f16* __restrict__ Pvi,
    f16* __restrict__ Por, f16* __restrict__ Poi) {
  __shared__ float2 t[64][65];
  int gid = blockIdx.x;
  int tsel = gid >> 11, r = gid & 2047;
  const float2* in;
  f16 *oR, *oI;
  int m0 = (r & 3) * 64, a0, bb, A, B;
  if (tsel == 3) {
    in = wo; oR = Por; oI = Poi;
    a0 = ((r >> 2) & 7) * 64; bb = r >> 5; A = 512; B = 64;
  } else {
    a0 = 0; bb = r >> 2; A = 64; B = 512;
    in = (tsel == 0) ? wq : (tsel == 1) ? wk : wv;
    oR = (tsel == 0) ? Pqr : (tsel == 1) ? Pkr : Pvr;
    oI = (tsel == 0) ? Pqi : (tsel == 1) ? Pki : Pvi;
  }
  int tid = threadIdx.x;
  for (int k = tid; k < 4096; k += 256) {
    int ai = k >> 6, mi = k & 63;
    t[ai][mi] = in[((size_t)(a0 + ai) * B + bb) * 256 + m0 + mi];
  }
  __syncthreads();
  for (int k = tid; k < 4096; k += 256) {
    int mi = k >> 6, ai = k & 63;
    float2 v = t[ai][mi];
    size_t o = (size_t)(m0 + mi) * 32768 + (size_t)bb * A + a0 + ai;
    oR[o] = (f16)v.x;
    oI[o] = (f16)v.y;
  }
}

// ---------------- K2: MFMA scores -> per-chunk partials --------------------
// grid (32 chunks, 8 h, 2 b), 256 thr (4 waves, 2x2 of 32x32 tiles).
__global__ __launch_bounds__(256, 2) void k_scores_m(
    const f16* __restrict__ Xr, const f16* __restrict__ Xi,
    const f16* __restrict__ Qwr, const f16* __restrict__ Qwi,
    const f16* __restrict__ Kwr, const f16* __restrict__ Kwi,
    float* __restrict__ part) {
  __shared__ __align__(16) unsigned char smem[65536];
  const int P_WQR = 0, P_WQI = 8192, P_WKR = 16384, P_WKI = 24576;
  const int P_QR = 32768, P_QI = 40960, P_KR = 49152, P_KI = 57344;
  int tid = threadIdx.x;
  int w = tid >> 6, lane = tid & 63, r = lane & 15, g = lane >> 4;
  int wr = w >> 1, wc = w & 1;
  int chunk = blockIdx.x, h = blockIdx.y, b = blockIdx.z;
  float4 Wst[2][8];
  auto LOADW = [&](int m, int sl) {
    const float4* gqr = (const float4*)Qwr + (size_t)m * 4096 + h * 512;
    const float4* gqi = (const float4*)Qwi + (size_t)m * 4096 + h * 512;
    const float4* gkr = (const float4*)Kwr + (size_t)m * 4096 + h * 512;
    const float4* gki = (const float4*)Kwi + (size_t)m * 4096 + h * 512;
    Wst[sl][0] = gqr[tid]; Wst[sl][1] = gqr[tid + 256];
    Wst[sl][2] = gqi[tid]; Wst[sl][3] = gqi[tid + 256];
    Wst[sl][4] = gkr[tid]; Wst[sl][5] = gkr[tid + 256];
    Wst[sl][6] = gki[tid]; Wst[sl][7] = gki[tid + 256];
  };
  f32x4 S[2][2] = {};
  LOADW(chunk * 8, 0);
#pragma unroll
  for (int mm = 0; mm < 8; ++mm) {
    const int cs = mm & 1;
    int m = chunk * 8 + mm;
    __syncthreads();  // all waves done reading LDS from prev iteration
#pragma unroll
    for (int it = 0; it < 2; ++it) {
      int s = tid + it * 256;
      int lo = swz128(s >> 3, s & 7);
      *(float4*)(smem + P_WQR + lo) = Wst[cs][0 + it];
      *(float4*)(smem + P_WQI + lo) = Wst[cs][2 + it];
      *(float4*)(smem + P_WKR + lo) = Wst[cs][4 + it];
      *(float4*)(smem + P_WKI + lo) = Wst[cs][6 + it];
    }
    __syncthreads();
    if (mm < 7) LOADW(m + 1, cs ^ 1);  // fly under Q/K GEMMs
    const f16x8* xr8 = (const f16x8*)Xr + (size_t)(b * 256 + m) * 512;
    const f16x8* xi8 = (const f16x8*)Xi + (size_t)(b * 256 + m) * 512;
    f16x8 axr[2][2], axi[2][2], axiN[2][2];
#pragma unroll
    for (int rt = 0; rt < 2; ++rt)
#pragma unroll
      for (int kt = 0; kt < 2; ++kt) {
        int idx = (32 * wr + rt * 16 + r) * 8 + kt * 4 + g;
        axr[rt][kt] = xr8[idx];
        axi[rt][kt] = xi8[idx];
        axiN[rt][kt] = -axi[rt][kt];
      }
    float lam = (m == 0) ? 1.0f : (((m & 15) == 0) ? 0.5f : 2.0f);
    // ---- Q = X*Wq (complex) ----
    {
      f32x4 cr[2][2] = {}, ci[2][2] = {};
      __builtin_amdgcn_s_setprio(1);
#pragma unroll
      for (int ct = 0; ct < 2; ++ct)
#pragma unroll
        for (int kt = 0; kt < 2; ++kt) {
          int lo = swz128(32 * wc + ct * 16 + r, kt * 4 + g);
          f16x8 bwr = *(const f16x8*)(smem + P_WQR + lo);
          f16x8 bwi = *(const f16x8*)(smem + P_WQI + lo);
#pragma unroll
          for (int rt = 0; rt < 2; ++rt) {
            cr[rt][ct] = MFMA(axr[rt][kt], bwr, cr[rt][ct]);
            cr[rt][ct] = MFMA(axiN[rt][kt], bwi, cr[rt][ct]);
            ci[rt][ct] = MFMA(axr[rt][kt], bwi, ci[rt][ct]);
            ci[rt][ct] = MFMA(axi[rt][kt], bwr, ci[rt][ct]);
          }
        }
      __builtin_amdgcn_s_setprio(0);
#pragma unroll
      for (int rt = 0; rt < 2; ++rt)
#pragma unroll
        for (int ct = 0; ct < 2; ++ct)
#pragma unroll
          for (int j = 0; j < 4; ++j) {
            int row = 32 * wr + rt * 16 + g * 4 + j;
            int col = 32 * wc + ct * 16 + r;
            *(f16*)(smem + P_QR + swzel(row, col)) = (f16)(cr[rt][ct][j] * lam);
            *(f16*)(smem + P_QI + swzel(row, col)) =
                (m == 0) ? (f16)0.f : (f16)(ci[rt][ct][j] * lam);
          }
    }
    // ---- K = X*Wk (complex) ----
    {
      f32x4 cr[2][2] = {}, ci[2][2] = {};
      __builtin_amdgcn_s_setprio(1);
#pragma unroll
      for (int ct = 0; ct < 2; ++ct)
#pragma unroll
        for (int kt = 0; kt < 2; ++kt) {
          int lo = swz128(32 * wc + ct * 16 + r, kt * 4 + g);
          f16x8 bwr = *(const f16x8*)(smem + P_WKR + lo);
          f16x8 bwi = *(const f16x8*)(smem + P_WKI + lo);
#pragma unroll
          for (int rt = 0; rt < 2; ++rt) {
            cr[rt][ct] = MFMA(axr[rt][kt], bwr, cr[rt][ct]);
            cr[rt][ct] = MFMA(axiN[rt][kt], bwi, cr[rt][ct]);
            ci[rt][ct] = MFMA(axr[rt][kt], bwi, ci[rt][ct]);
            ci[rt][ct] = MFMA(axi[rt][kt], bwr, ci[rt][ct]);
          }
        }
      __builtin_amdgcn_s_setprio(0);
#pragma unroll
      for (int rt = 0; rt < 2; ++rt)
#pragma unroll
        for (int ct = 0; ct < 2; ++ct)
#pragma unroll
          for (int j = 0; j < 4; ++j) {
            int row = 32 * wr + rt * 16 + g * 4 + j;
            int col = 32 * wc + ct * 16 + r;
            *(f16*)(smem + P_KR + swzel(row, col)) = (f16)cr[rt][ct][j];
            *(f16*)(smem + P_KI + swzel(row, col)) = (f16)ci[rt][ct][j];
          }
    }
    __syncthreads();
    // ---- S += Qr*Kr^T + Qi*Ki^T ----
    {
      f16x8 aqr[2][2], aqi[2][2];
#pragma unroll
      for (int rt = 0; rt < 2; ++rt)
#pragma unroll
        for (int kt = 0; kt < 2; ++kt) {
          int lo = swz128(32 * wr + rt * 16 + r, kt * 4 + g);
          aqr[rt][kt] = *(const f16x8*)(smem + P_QR + lo);
          aqi[rt][kt] = *(const f16x8*)(smem + P_QI + lo);
        }
      __builtin_amdgcn_s_setprio(1);
#pragma unroll
      for (int ct = 0; ct < 2; ++ct)
#pragma unroll
        for (int kt = 0; kt < 2; ++kt) {
          int lo = swz128(32 * wc + ct * 16 + r, kt * 4 + g);
          f16x8 bkr = *(const f16x8*)(smem + P_KR + lo);
          f16x8 bki = *(const f16x8*)(smem + P_KI + lo);
#pragma unroll
          for (int rt = 0; rt < 2; ++rt) {
            S[rt][ct] = MFMA(aqr[rt][kt], bkr, S[rt][ct]);
            S[rt][ct] = MFMA(aqi[rt][kt], bki, S[rt][ct]);
          }
        }
      __builtin_amdgcn_s_setprio(0);
    }
  }
  const float fac = 1.0f / 262144.0f;
  float* dst = part + ((size_t)(chunk * 16 + b * 8 + h)) * 4096;
#pragma unroll
  for (int rt = 0; rt < 2; ++rt)
#pragma unroll
    for (int ct = 0; ct < 2; ++ct)
#pragma unroll
      for (int j = 0; j < 4; ++j) {
        int s_ = 32 * wr + rt * 16 + g * 4 + j;
        int t_ = 32 * wc + ct * 16 + r;
        dst[s_ * 64 + t_] = S[rt][ct][j] * fac;
      }
}

// ---------------- K3: sum partials + log-CPB bias + softmax -> fp16 attn ---
__global__ __launch_bounds__(64) void k_softmax(const float* __restrict__ part,
                                                const float* __restrict__ w1,
                                                const float* __restrict__ b1,
                                                const float* __restrict__ w2,
                                                const float* __restrict__ b2,
                                                f16* __restrict__ at) {
  int id = blockIdx.x;
  int s = id & 63;
  int h = (id >> 6) & 7;
  int bh = id >> 6;
  int t = threadIdx.x;
  float v = 0.f;
#pragma unroll
  for (int ch = 0; ch < 32; ++ch)
    v += part[((size_t)(ch * 16 + bh)) * 4096 + s * 64 + t];
  float d0 = (float)((s >> 3) - (t >> 3)) * (8.0f / 7.0f);
  float d1 = (float)((s & 7) - (t & 7)) * (8.0f / 7.0f);
  float a0 = log2f(fabsf(d0) + 1.0f) * (1.0f / 3.0f);
  float a1 = log2f(fabsf(d1) + 1.0f) * (1.0f / 3.0f);
  float r0 = (d0 < 0.f) ? -a0 : a0;
  float r1 = (d1 < 0.f) ? -a1 : a1;
  float acc = b2[h];
  for (int c = 0; c < 64; ++c) {
    float hv = fmaf(r0, w1[c], fmaf(r1, w1[64 + c], b1[c]));
    hv = fmaxf(hv, 0.0f);
    acc = fmaf(hv, w2[c * 8 + h], acc);
  }
  float bias = 16.0f / (1.0f + expf(-acc));
  v += bias;
  float mx = v;
  for (int o = 32; o; o >>= 1) mx = fmaxf(mx, __shfl_xor(mx, o));
  float e = expf(v - mx);
  float sm = e;
  for (int o = 32; o; o >>= 1) sm += __shfl_xor(sm, o);
  at[(size_t)id * 64 + t] = (f16)(e / sm);
}

// ---------------- K4: MFMA V-path -> Ff2[m][b*4096+s*64+c] -----------------
__global__ __launch_bounds__(256, 2) void k_vpath_m(
    const f16* __restrict__ Xr, const f16* __restrict__ Xi,
    const f16* __restrict__ Vwr, const f16* __restrict__ Vwi,
    const f16* __restrict__ Owr, const f16* __restrict__ Owi,
    const f16* __restrict__ At, float2* __restrict__ Ff2) {
  __shared__ __align__(16) unsigned char smem[73728];
  const int P_WVR = 0, P_WVI = 8192, P_WOR = 16384, P_WOI = 24576;
  const int P_VTR = 32768, P_VTI = 40960, P_YR = 49152, P_YI = 57344;
  const int P_AT = 65536;
  int tid = threadIdx.x;
  int w = tid >> 6, lane = tid & 63, r = lane & 15, g = lane >> 4;
  int wr = w >> 1, wc = w & 1;
  int m = blockIdx.x, b = blockIdx.y;
  // X fragments once per block
  const f16x8* xr8 = (const f16x8*)Xr + (size_t)(b * 256 + m) * 512;
  const f16x8* xi8 = (const f16x8*)Xi + (size_t)(b * 256 + m) * 512;
  f16x8 axr[2][2], axi[2][2], axiN[2][2];
#pragma unroll
  for (int rt = 0; rt < 2; ++rt)
#pragma unroll
    for (int kt = 0; kt < 2; ++kt) {
      int idx = (32 * wr + rt * 16 + r) * 8 + kt * 4 + g;
      axr[rt][kt] = xr8[idx];
      axi[rt][kt] = xi8[idx];
      axiN[rt][kt] = -axi[rt][kt];
    }
  float mu = (m == 0) ? 1.0f : (((m & 15) == 0) ? 0.5f : 2.0f);
  float4 Vst[2][10];
  auto LOADH = [&](int h, int sl) {
    const float4* gvr = (const float4*)Vwr + (size_t)m * 4096 + h * 512;
    const float4* gvi = (const float4*)Vwi + (size_t)m * 4096 + h * 512;
    const float4* gor = (const float4*)Owr + (size_t)m * 4096 + h * 8;
    const float4* goi = (const float4*)Owi + (size_t)m * 4096 + h * 8;
    const float4* gat = (const float4*)At + (size_t)(b * 8 + h) * 512;
    Vst[sl][0] = gvr[tid]; Vst[sl][1] = gvr[tid + 256];
    Vst[sl][2] = gvi[tid]; Vst[sl][3] = gvi[tid + 256];
    int r0_ = tid >> 3, s0_ = tid & 7;
    Vst[sl][4] = gor[r0_ * 64 + s0_]; Vst[sl][5] = gor[(r0_ + 32) * 64 + s0_];
    Vst[sl][6] = goi[r0_ * 64 + s0_]; Vst[sl][7] = goi[(r0_ + 32) * 64 + s0_];
    Vst[sl][8] = gat[tid]; Vst[sl][9] = gat[tid + 256];
  };
  f32x4 fr[2][2] = {}, fi_[2][2] = {};
  LOADH(0, 0);
#pragma unroll
  for (int h = 0; h < 8; ++h) {
    const int cs = h & 1;
    __syncthreads();  // prev F-GEMM / VT / At reads complete
#pragma unroll
    for (int it = 0; it < 2; ++it) {
      int s = tid + it * 256;
      int lo = swz128(s >> 3, s & 7);
      *(float4*)(smem + P_WVR + lo) = Vst[cs][0 + it];
      *(float4*)(smem + P_WVI + lo) = Vst[cs][2 + it];
      *(float4*)(smem + P_WOR + lo) = Vst[cs][4 + it];
      *(float4*)(smem + P_WOI + lo) = Vst[cs][6 + it];
      *(float4*)(smem + P_AT + lo) = Vst[cs][8 + it];
    }
    __syncthreads();
    if (h < 7) LOADH(h + 1, cs ^ 1);  // fly under V-GEMM
    // ---- V = mu * X*Wv (complex, DC imag zero), store transposed VT[d][t]
    {
      f32x4 vr[2][2] = {}, vi[2][2] = {};
      __builtin_amdgcn_s_setprio(1);
#pragma unroll
      for (int ct = 0; ct < 2; ++ct)
#pragma unroll
        for (int kt = 0; kt < 2; ++kt) {
          int lo = swz128(32 * wc + ct * 16 + r, kt * 4 + g);
          f16x8 bwr = *(const f16x8*)(smem + P_WVR + lo);
          f16x8 bwi = *(const f16x8*)(smem + P_WVI + lo);
#pragma unroll
          for (int rt = 0; rt < 2; ++rt) {
            vr[rt][ct] = MFMA(axr[rt][kt], bwr, vr[rt][ct]);
            vr[rt][ct] = MFMA(axiN[rt][kt], bwi, vr[rt][ct]);
            vi[rt][ct] = MFMA(axr[rt][kt], bwi, vi[rt][ct]);
            vi[rt][ct] = MFMA(axi[rt][kt], bwr, vi[rt][ct]);
          }
        }
      __builtin_amdgcn_s_setprio(0);
#pragma unroll
      for (int rt = 0; rt < 2; ++rt)
#pragma unroll
        for (int ct = 0; ct < 2; ++ct) {
          int drow = 32 * wc + ct * 16 + r;
          int t0 = 32 * wr + rt * 16 + g * 4;
          f16x4 pr, pi;
#pragma unroll
          for (int j = 0; j < 4; ++j) {
            pr[j] = (f16)(vr[rt][ct][j] * mu);
            pi[j] = (m == 0) ? (f16)0.f : (f16)(vi[rt][ct][j] * mu);
          }
          int lo = swzel(drow, t0);
          *(f16x4*)(smem + P_VTR + lo) = pr;
          *(f16x4*)(smem + P_VTI + lo) = pi;
        }
    }
    __syncthreads();
    // ---- Y = At * V ----
    {
      f16x8 aat[2][2];
#pragma unroll
      for (int rt = 0; rt < 2; ++rt)
#pragma unroll
        for (int kt = 0; kt < 2; ++kt)
          aat[rt][kt] = *(const f16x8*)(
              smem + P_AT + swz128(32 * wr + rt * 16 + r, kt * 4 + g));
      f32x4 yr[2][2] = {}, yi[2][2] = {};
      __builtin_amdgcn_s_setprio(1);
#pragma unroll
      for (int ct = 0; ct < 2; ++ct)
#pragma unroll
        for (int kt = 0; kt < 2; ++kt) {
          int lo = swz128(32 * wc + ct * 16 + r, kt * 4 + g);
          f16x8 bvr = *(const f16x8*)(smem + P_VTR + lo);
          f16x8 bvi = *(const f16x8*)(smem + P_VTI + lo);
#pragma unroll
          for (int rt = 0; rt < 2; ++rt) {
            yr[rt][ct] = MFMA(aat[rt][kt], bvr, yr[rt][ct]);
            yi[rt][ct] = MFMA(aat[rt][kt], bvi, yi[rt][ct]);
          }
        }
      __builtin_amdgcn_s_setprio(0);
#pragma unroll
      for (int rt = 0; rt < 2; ++rt)
#pragma unroll
        for (int ct = 0; ct < 2; ++ct)
#pragma unroll
          for (int j = 0; j < 4; ++j) {
            int row = 32 * wr + rt * 16 + g * 4 + j;
            int col = 32 * wc + ct * 16 + r;
            *(f16*)(smem + P_YR + swzel(row, col)) = (f16)yr[rt][ct][j];
            *(f16*)(smem + P_YI + swzel(row, col)) = (f16)yi[rt][ct][j];
          }
    }
    __syncthreads();
    // ---- F += Y * Wo (complex) ----
    {
      f16x8 ayr[2][2], ayi[2][2], ayiN[2][2];
#pragma unroll
      for (int rt = 0; rt < 2; ++rt)
#pragma unroll
        for (int kt = 0; kt < 2; ++kt) {
          int lo = swz128(32 * wr + rt * 16 + r, kt * 4 + g);
          ayr[rt][kt] = *(const f16x8*)(smem + P_YR + lo);
          ayi[rt][kt] = *(const f16x8*)(smem + P_YI + lo);
          ayiN[rt][kt] = -ayi[rt][kt];
        }
      __builtin_amdgcn_s_setprio(1);
#pragma unroll
      for (int ct = 0; ct < 2; ++ct)
#pragma unroll
        for (int kt = 0; kt < 2; ++kt) {
          int lo = swz128(32 * wc + ct * 16 + r, kt * 4 + g);
          f16x8 bor = *(const f16x8*)(smem + P_WOR + lo);
          f16x8 boi = *(const f16x8*)(smem + P_WOI + lo);
#pragma unroll
          for (int rt = 0; rt < 2; ++rt) {
            fr[rt][ct] = MFMA(ayr[rt][kt], bor, fr[rt][ct]);
            fr[rt][ct] = MFMA(ayiN[rt][kt], boi, fr[rt][ct]);
            fi_[rt][ct] = MFMA(ayr[rt][kt], boi, fi_[rt][ct]);
            fi_[rt][ct] = MFMA(ayi[rt][kt], bor, fi_[rt][ct]);
          }
        }
      __builtin_amdgcn_s_setprio(0);
    }
  }
  // coalesced m-major store (block-contiguous 32KB region)
  float2* dst = Ff2 + (size_t)m * 8192 + (size_t)b * 4096;
#pragma unroll
  for (int rt = 0; rt < 2; ++rt)
#pragma unroll
    for (int ct = 0; ct < 2; ++ct)
#pragma unroll
      for (int j = 0; j < 4; ++j) {
        int s_ = 32 * wr + rt * 16 + g * 4 + j;
        int c_ = 32 * wc + ct * 16 + r;
        dst[s_ * 64 + c_] = make_float2(fr[rt][ct][j], fi_[rt][ct][j]);
      }
}

// ---------------- K-tr: Ff2[m][f] -> Ff[f][m] (LDS tile transpose) ---------
__global__ __launch_bounds__(256) void k_tr(const float2* __restrict__ Ff2,
                                            float2* __restrict__ Ff) {
  __shared__ float2 t[64][65];
  int m0 = blockIdx.x * 64, f0 = blockIdx.y * 64;
  int tid = threadIdx.x;
  for (int k = tid; k < 4096; k += 256) {
    int mi = k >> 6, fj = k & 63;
    t[mi][fj] = Ff2[(size_t)(m0 + mi) * 8192 + f0 + fj];
  }
  __syncthreads();
  for (int k = tid; k < 4096; k += 256) {
    int fj = k >> 6, mi = k & 63;
    Ff[(size_t)(f0 + fj) * 256 + m0 + mi] = t[mi][fj];
  }
}

// ---------------- K5: inverse DFT -----------------------------------------
__global__ __launch_bounds__(256) void k_idft(const float2* __restrict__ Ff,
                                              float* __restrict__ out) {
  __shared__ float2 Fm[256];
  __shared__ float2 g[32][17];
  __shared__ float2 tw[32];
  int f = blockIdx.x;
  int tid = threadIdx.x;
  if (tid < 32) {
    float a = (2.0f * PI_F / 32.0f) * (float)tid;
    tw[tid] = make_float2(cosf(a), sinf(a));
  }
  Fm[tid] = Ff[(size_t)f * 256 + tid];
  __syncthreads();
  for (int o = tid; o < 512; o += 256) {
    int x = o >> 4, q = o & 15;
    float gr = 0.f, gi = 0.f;
#pragma unroll
    for (int p = 0; p < 16; ++p) {
      float2 a = Fm[p * 16 + q];
      float2 w = tw[(p * x) & 31];
      gr += a.x * w.x - a.y * w.y;
      gi += a.x * w.y + a.y * w.x;
    }
    g[x][q] = make_float2(gr, gi);
  }
  __syncthreads();
  int x = tid >> 3, j0 = (tid & 7) * 4;
  float4 r;
  float* rr = &r.x;
#pragma unroll
  for (int jj = 0; jj < 4; ++jj) {
    int j = j0 + jj;
    float acc = 0.f;
#pragma unroll
    for (int q = 0; q < 16; ++q) {
      float2 gv = g[x][q];
      float2 w = tw[(q * j) & 31];
      acc += gv.x * w.x - gv.y * w.y;
    }
    rr[jj] = acc * (1.0f / 1024.0f);
  }
  *(float4*)(out + (size_t)f * 1024 + x * 32 + j0) = r;
}

extern "C" void kernel_launch(void* const* d_in, const int* in_sizes, int n_in,
                              void* d_out, int out_size, void* d_ws,
                              size_t ws_size, hipStream_t stream) {
  const float* seq = (const float*)d_in[0];
  const float2* wq = (const float2*)d_in[1];
  const float2* wk = (const float2*)d_in[2];
  const float2* wv = (const float2*)d_in[3];
  const float2* wo = (const float2*)d_in[4];
  const float* w1 = (const float*)d_in[5];
  const float* b1 = (const float*)d_in[6];
  const float* w2 = (const float*)d_in[7];
  const float* b2 = (const float*)d_in[8];
  float* out = (float*)d_out;

  // ws layout (peak 167,903,232 B; proven ws_size >= 168,034,304 in R1)
  char* ws = (char*)d_ws;
  f16* Xr = (f16*)(ws + 0);                    //  4 MB
  f16* Xi = (f16*)(ws + 4194304);              //  4 MB
  float* part = (float*)(ws + 8388608);        //  8 MB [32][16][4096]
  f16* At = (f16*)(ws + 16777216);             //  128 KB
  float2* Ff2 = (float2*)(ws + 16908288);      //  16 MB [m][f]
  f16* Pqr = (f16*)(ws + 33685504);
  f16* Pqi = (f16*)(ws + 50462720);
  f16* Pkr = (f16*)(ws + 67239936);
  f16* Pki = (f16*)(ws + 84017152);
  f16* Pvr = (f16*)(ws + 100794368);
  f16* Pvi = (f16*)(ws + 117571584);
  f16* Por = (f16*)(ws + 134348800);
  f16* Poi = (f16*)(ws + 151126016);           // ends 167,903,232
  float2* Ff = (float2*)(ws + 33685504);       // alias on Pqr/Pqi (dead then)

  k_dft<<<8192, 256, 0, stream>>>(seq, Xr, Xi);
  k_repack_all<<<8192, 256, 0, stream>>>(wq, wk, wv, wo, Pqr, Pqi, Pkr, Pki,
                                         Pvr, Pvi, Por, Poi);
  k_scores_m<<<dim3(32, 8, 2), 256, 0, stream>>>(Xr, Xi, Pqr, Pqi, Pkr, Pki,
                                                 part);
  k_softmax<<<1024, 64, 0, stream>>>(part, w1, b1, w2, b2, At);
  k_vpath_m<<<dim3(256, 2), 256, 0, stream>>>(Xr, Xi, Pvr, Pvi, Por, Poi, At,
                                              Ff2);
  k_tr<<<dim3(4, 128), 256, 0, stream>>>(Ff2, Ff);
  k_idft<<<8192, 256, 0, stream>>>(Ff, out);
}

// Round 5
// 262.329 us; speedup vs baseline: 1.4283x; 1.4283x over previous
//
#include <hip/hip_runtime.h>
#include <math.h>

// B=2, S=64, C=64, NH=8, H=W=32, M1=M2=16 (256 modes), mode m=p*16+q.
// lambda/mu: m==0 -> 1 (imag zeroed), m%16==0 -> 0.5, else 2.

#define PI_F 3.14159265358979323846f

typedef _Float16 f16;
typedef f16 f16x8 __attribute__((ext_vector_type(8)));
typedef f16 f16x4 __attribute__((ext_vector_type(4)));
typedef float f32x4 __attribute__((ext_vector_type(4)));

#define MFMA(a, b, c) __builtin_amdgcn_mfma_f32_16x16x32_f16(a, b, c, 0, 0, 0)

// byte offset of a 16B slot in an 8KB [64 rows][64 f16] plane, XOR-swizzled
__device__ __forceinline__ int swz128(int row, int slot) {
  return (row << 7) + (((slot) ^ (row & 7)) << 4);
}
// byte offset of one f16 element (same swizzle)
__device__ __forceinline__ int swzel(int row, int col) {
  return (row << 7) + ((((col) >> 3) ^ (row & 7)) << 4) + (((col) & 7) << 1);
}

// ---------------- K1: forward DFT -> fp16 re/im planes [b][m][s*64+i] ------
__global__ __launch_bounds__(256) void k_dft(const float* __restrict__ seq,
                                             f16* __restrict__ Xr,
                                             f16* __restrict__ Xi) {
  __shared__ float fld[32][33];
  __shared__ float2 tb[32][17];
  __shared__ float2 tw[32];
  int f = blockIdx.x;
  int tid = threadIdx.x;
  if (tid < 32) {
    float a = (2.0f * PI_F / 32.0f) * (float)tid;
    tw[tid] = make_float2(cosf(a), sinf(a));
  }
  const float4* s4 = (const float4*)(seq + (size_t)f * 1024);
  float4 v = s4[tid];
  int x0 = tid >> 3, y0 = (tid & 7) * 4;
  fld[x0][y0 + 0] = v.x; fld[x0][y0 + 1] = v.y;
  fld[x0][y0 + 2] = v.z; fld[x0][y0 + 3] = v.w;
  __syncthreads();
  for (int o = tid; o < 512; o += 256) {
    int x = o >> 4, q = o & 15;
    float re = 0.f, im = 0.f;
#pragma unroll
    for (int y = 0; y < 32; ++y) {
      float val = fld[x][y];
      float2 w = tw[(q * y) & 31];
      re = fmaf(val, w.x, re);
      im = fmaf(val, -w.y, im);
    }
    tb[x][q] = make_float2(re, im);
  }
  __syncthreads();
  int p = tid >> 4, q = tid & 15;
  float re = 0.f, im = 0.f;
#pragma unroll
  for (int x = 0; x < 32; ++x) {
    float2 t = tb[x][q];
    float2 w = tw[(p * x) & 31];
    re += w.x * t.x + w.y * t.y;
    im += w.x * t.y - w.y * t.x;
  }
  int b = f >> 12;
  int si = f & 4095;
  size_t o = (size_t)(b * 256 + tid) * 4096 + si;
  Xr[o] = (f16)re;
  Xi[o] = (f16)im;
}

// ---------------- K-repack (single launch, vectorized 16B writes) ----------
// q/k/v: raw [i(64)][hd(512)][m], planes [m][hd*64+i]
// wo:    raw [hd(512)][c(64)][m], planes [m][c*512+hd]
// Per block: 64 rows (a) x 64 modes. LDS tile stored TRANSPOSED [mode][a]
// (pitch 72 f16 = 144B, 16B-aligned rows) so the write phase emits f16x8.
__global__ __launch_bounds__(256) void k_repack_all(
    const float2* __restrict__ wq, const float2* __restrict__ wk,
    const float2* __restrict__ wv, const float2* __restrict__ wo,
    f16* __restrict__ Pqr, f16* __restrict__ Pqi, f16* __restrict__ Pkr,
    f16* __restrict__ Pki, f16* __restrict__ Pvr, f16* __restrict__ Pvi,
    f16* __restrict__ Por, f16* __restrict__ Poi) {
  __shared__ f16 tR[64][72];
  __shared__ f16 tI[64][72];
  int gid = blockIdx.x;
  int tsel = gid >> 11, r = gid & 2047;
  const float2* in;
  f16 *oR, *oI;
  int m0 = (r & 3) * 64, a0, bb, A, B;
  if (tsel == 3) {
    in = wo; oR = Por; oI = Poi;
    a0 = ((r >> 2) & 7) * 64; bb = r >> 5; A = 512; B = 64;
  } else {
    a0 = 0; bb = r >> 2; A = 64; B = 512;
    in = (tsel == 0) ? wq : (tsel == 1) ? wk : wv;
    oR = (tsel == 0) ? Pqr : (tsel == 1) ? Pkr : Pvr;
    oI = (tsel == 0) ? Pqi : (tsel == 1) ? Pki : Pvi;
  }
  int tid = threadIdx.x;
  const float4* in4 = (const float4*)in;
  // read: 2048 float4 (each = 2 consecutive modes of one row), 8 per thread
  for (int k = tid; k < 2048; k += 256) {
    int ai = k >> 5, mj = k & 31;
    float4 v = in4[((size_t)(a0 + ai) * B + bb) * 128 + (m0 >> 1) + mj];
    tR[2 * mj + 0][ai] = (f16)v.x;
    tI[2 * mj + 0][ai] = (f16)v.y;
    tR[2 * mj + 1][ai] = (f16)v.z;
    tI[2 * mj + 1][ai] = (f16)v.w;
  }
  __syncthreads();
  // write: 512 f16x8 slots per plane, fully coalesced 16B/lane
  for (int k = tid; k < 1024; k += 256) {
    int pl = k >> 9, s = k & 511;
    int mi = s >> 3, a8 = (s & 7) * 8;
    f16x8 v = pl ? *(const f16x8*)&tI[mi][a8] : *(const f16x8*)&tR[mi][a8];
    f16* dst = pl ? oI : oR;
    *(f16x8*)&dst[(size_t)(m0 + mi) * 32768 + (size_t)bb * A + a0 + a8] = v;
  }
}

// ---------------- K2: MFMA scores (R3 body) --------------------------------
// grid (32 chunks, 8 h, 2 b), 256 thr (4 waves, 2x2 of 32x32 tiles).
__global__ __launch_bounds__(256, 2) void k_scores_m(
    const f16* __restrict__ Xr, const f16* __restrict__ Xi,
    const f16* __restrict__ Qwr, const f16* __restrict__ Qwi,
    const f16* __restrict__ Kwr, const f16* __restrict__ Kwi,
    float* __restrict__ scores) {
  __shared__ __align__(16) unsigned char smem[65536];
  const int P_WQR = 0, P_WQI = 8192, P_WKR = 16384, P_WKI = 24576;
  const int P_QR = 32768, P_QI = 40960, P_KR = 49152, P_KI = 57344;
  int tid = threadIdx.x;
  int w = tid >> 6, lane = tid & 63, r = lane & 15, g = lane >> 4;
  int wr = w >> 1, wc = w & 1;
  int chunk = blockIdx.x, h = blockIdx.y, b = blockIdx.z;
  f32x4 S[2][2] = {};
  for (int mm = 0; mm < 8; ++mm) {
    int m = chunk * 8 + mm;
    const f16x8* xr8 = (const f16x8*)Xr + (size_t)(b * 256 + m) * 512;
    const f16x8* xi8 = (const f16x8*)Xi + (size_t)(b * 256 + m) * 512;
    f16x8 axr[2][2], axi[2][2], axiN[2][2];
#pragma unroll
    for (int rt = 0; rt < 2; ++rt)
#pragma unroll
      for (int kt = 0; kt < 2; ++kt) {
        int idx = (32 * wr + rt * 16 + r) * 8 + kt * 4 + g;
        axr[rt][kt] = xr8[idx];
        axi[rt][kt] = xi8[idx];
        axiN[rt][kt] = -axi[rt][kt];
      }
    const float4* gqr = (const float4*)Qwr + (size_t)m * 4096 + h * 512;
    const float4* gqi = (const float4*)Qwi + (size_t)m * 4096 + h * 512;
    const float4* gkr = (const float4*)Kwr + (size_t)m * 4096 + h * 512;
    const float4* gki = (const float4*)Kwi + (size_t)m * 4096 + h * 512;
#pragma unroll
    for (int it = 0; it < 2; ++it) {
      int s = tid + it * 256;
      int row = s >> 3, sl = s & 7;
      int lo = swz128(row, sl);
      *(float4*)(smem + P_WQR + lo) = gqr[s];
      *(float4*)(smem + P_WQI + lo) = gqi[s];
      *(float4*)(smem + P_WKR + lo) = gkr[s];
      *(float4*)(smem + P_WKI + lo) = gki[s];
    }
    __syncthreads();
    float lam = (m == 0) ? 1.0f : (((m & 15) == 0) ? 0.5f : 2.0f);
    // ---- Q = X*Wq (complex) ----
    {
      f32x4 cr[2][2] = {}, ci[2][2] = {};
#pragma unroll
      for (int ct = 0; ct < 2; ++ct)
#pragma unroll
        for (int kt = 0; kt < 2; ++kt) {
          int lo = swz128(32 * wc + ct * 16 + r, kt * 4 + g);
          f16x8 bwr = *(const f16x8*)(smem + P_WQR + lo);
          f16x8 bwi = *(const f16x8*)(smem + P_WQI + lo);
#pragma unroll
          for (int rt = 0; rt < 2; ++rt) {
            cr[rt][ct] = MFMA(axr[rt][kt], bwr, cr[rt][ct]);
            cr[rt][ct] = MFMA(axiN[rt][kt], bwi, cr[rt][ct]);
            ci[rt][ct] = MFMA(axr[rt][kt], bwi, ci[rt][ct]);
            ci[rt][ct] = MFMA(axi[rt][kt], bwr, ci[rt][ct]);
          }
        }
#pragma unroll
      for (int rt = 0; rt < 2; ++rt)
#pragma unroll
        for (int ct = 0; ct < 2; ++ct)
#pragma unroll
          for (int j = 0; j < 4; ++j) {
            int row = 32 * wr + rt * 16 + g * 4 + j;
            int col = 32 * wc + ct * 16 + r;
            *(f16*)(smem + P_QR + swzel(row, col)) = (f16)(cr[rt][ct][j] * lam);
            *(f16*)(smem + P_QI + swzel(row, col)) =
                (m == 0) ? (f16)0.f : (f16)(ci[rt][ct][j] * lam);
          }
    }
    // ---- K = X*Wk (complex) ----
    {
      f32x4 cr[2][2] = {}, ci[2][2] = {};
#pragma unroll
      for (int ct = 0; ct < 2; ++ct)
#pragma unroll
        for (int kt = 0; kt < 2; ++kt) {
          int lo = swz128(32 * wc + ct * 16 + r, kt * 4 + g);
          f16x8 bwr = *(const f16x8*)(smem + P_WKR + lo);
          f16x8 bwi = *(const f16x8*)(smem + P_WKI + lo);
#pragma unroll
          for (int rt = 0; rt < 2; ++rt) {
            cr[rt][ct] = MFMA(axr[rt][kt], bwr, cr[rt][ct]);
            cr[rt][ct] = MFMA(axiN[rt][kt], bwi, cr[rt][ct]);
            ci[rt][ct] = MFMA(axr[rt][kt], bwi, ci[rt][ct]);
            ci[rt][ct] = MFMA(axi[rt][kt], bwr, ci[rt][ct]);
          }
        }
#pragma unroll
      for (int rt = 0; rt < 2; ++rt)
#pragma unroll
        for (int ct = 0; ct < 2; ++ct)
#pragma unroll
          for (int j = 0; j < 4; ++j) {
            int row = 32 * wr + rt * 16 + g * 4 + j;
            int col = 32 * wc + ct * 16 + r;
            *(f16*)(smem + P_KR + swzel(row, col)) = (f16)cr[rt][ct][j];
            *(f16*)(smem + P_KI + swzel(row, col)) = (f16)ci[rt][ct][j];
          }
    }
    __syncthreads();
    // ---- S += Qr*Kr^T + Qi*Ki^T ----
    {
      f16x8 aqr[2][2], aqi[2][2];
#pragma unroll
      for (int rt = 0; rt < 2; ++rt)
#pragma unroll
        for (int kt = 0; kt < 2; ++kt) {
          int lo = swz128(32 * wr + rt * 16 + r, kt * 4 + g);
          aqr[rt][kt] = *(const f16x8*)(smem + P_QR + lo);
          aqi[rt][kt] = *(const f16x8*)(smem + P_QI + lo);
        }
#pragma unroll
      for (int ct = 0; ct < 2; ++ct)
#pragma unroll
        for (int kt = 0; kt < 2; ++kt) {
          int lo = swz128(32 * wc + ct * 16 + r, kt * 4 + g);
          f16x8 bkr = *(const f16x8*)(smem + P_KR + lo);
          f16x8 bki = *(const f16x8*)(smem + P_KI + lo);
#pragma unroll
          for (int rt = 0; rt < 2; ++rt) {
            S[rt][ct] = MFMA(aqr[rt][kt], bkr, S[rt][ct]);
            S[rt][ct] = MFMA(aqi[rt][kt], bki, S[rt][ct]);
          }
        }
    }
    __syncthreads();
  }
  const float fac = 1.0f / 262144.0f;
  float* dst = scores + ((size_t)(b * 8 + h)) * 4096;
#pragma unroll
  for (int rt = 0; rt < 2; ++rt)
#pragma unroll
    for (int ct = 0; ct < 2; ++ct)
#pragma unroll
      for (int j = 0; j < 4; ++j) {
        int s_ = 32 * wr + rt * 16 + g * 4 + j;
        int t_ = 32 * wc + ct * 16 + r;
        atomicAdd(&dst[s_ * 64 + t_], S[rt][ct][j] * fac);
      }
}

// ---------------- K3: log-CPB bias + softmax -> fp16 attn -----------------
__global__ __launch_bounds__(64) void k_softmax(const float* __restrict__ scores,
                                                const float* __restrict__ w1,
                                                const float* __restrict__ b1,
                                                const float* __restrict__ w2,
                                                const float* __restrict__ b2,
                                                f16* __restrict__ at) {
  int id = blockIdx.x;
  int s = id & 63;
  int h = (id >> 6) & 7;
  int t = threadIdx.x;
  float d0 = (float)((s >> 3) - (t >> 3)) * (8.0f / 7.0f);
  float d1 = (float)((s & 7) - (t & 7)) * (8.0f / 7.0f);
  float a0 = log2f(fabsf(d0) + 1.0f) * (1.0f / 3.0f);
  float a1 = log2f(fabsf(d1) + 1.0f) * (1.0f / 3.0f);
  float r0 = (d0 < 0.f) ? -a0 : a0;
  float r1 = (d1 < 0.f) ? -a1 : a1;
  float acc = b2[h];
  for (int c = 0; c < 64; ++c) {
    float hv = fmaf(r0, w1[c], fmaf(r1, w1[64 + c], b1[c]));
    hv = fmaxf(hv, 0.0f);
    acc = fmaf(hv, w2[c * 8 + h], acc);
  }
  float bias = 16.0f / (1.0f + expf(-acc));
  size_t base = (size_t)id * 64;
  float v = scores[base + t] + bias;
  float mx = v;
  for (int o = 32; o; o >>= 1) mx = fmaxf(mx, __shfl_xor(mx, o));
  float e = expf(v - mx);
  float sm = e;
  for (int o = 32; o; o >>= 1) sm += __shfl_xor(sm, o);
  at[base + t] = (f16)(e / sm);
}

// ---------------- K4: MFMA V-path (R3 body) --------------------------------
// grid (256 m, 2 b), 256 thr. F accumulated in regs across 8 heads.
__global__ __launch_bounds__(256, 2) void k_vpath_m(
    const f16* __restrict__ Xr, const f16* __restrict__ Xi,
    const f16* __restrict__ Vwr, const f16* __restrict__ Vwi,
    const f16* __restrict__ Owr, const f16* __restrict__ Owi,
    const f16* __restrict__ At, float2* __restrict__ Ff) {
  __shared__ __align__(16) unsigned char smem[73728];
  const int P_WVR = 0, P_WVI = 8192, P_WOR = 16384, P_WOI = 24576;
  const int P_VTR = 32768, P_VTI = 40960, P_YR = 49152, P_YI = 57344;
  const int P_AT = 65536;
  int tid = threadIdx.x;
  int w = tid >> 6, lane = tid & 63, r = lane & 15, g = lane >> 4;
  int wr = w >> 1, wc = w & 1;
  int m = blockIdx.x, b = blockIdx.y;
  const f16x8* xr8 = (const f16x8*)Xr + (size_t)(b * 256 + m) * 512;
  const f16x8* xi8 = (const f16x8*)Xi + (size_t)(b * 256 + m) * 512;
  f16x8 axr[2][2], axi[2][2], axiN[2][2];
#pragma unroll
  for (int rt = 0; rt < 2; ++rt)
#pragma unroll
    for (int kt = 0; kt < 2; ++kt) {
      int idx = (32 * wr + rt * 16 + r) * 8 + kt * 4 + g;
      axr[rt][kt] = xr8[idx];
      axi[rt][kt] = xi8[idx];
      axiN[rt][kt] = -axi[rt][kt];
    }
  float mu = (m == 0) ? 1.0f : (((m & 15) == 0) ? 0.5f : 2.0f);
  f32x4 fr[2][2] = {}, fi_[2][2] = {};
  for (int h = 0; h < 8; ++h) {
    __syncthreads();  // prev F-GEMM (reads Y/WO) done before restaging
    const float4* gvr = (const float4*)Vwr + (size_t)m * 4096 + h * 512;
    const float4* gvi = (const float4*)Vwi + (size_t)m * 4096 + h * 512;
    const float4* gor = (const float4*)Owr + (size_t)m * 4096 + h * 8;
    const float4* goi = (const float4*)Owi + (size_t)m * 4096 + h * 8;
    const float4* gat = (const float4*)At + (size_t)(b * 8 + h) * 512;
#pragma unroll
    for (int it = 0; it < 2; ++it) {
      int s = tid + it * 256;
      int row = s >> 3, sl = s & 7;
      int lo = swz128(row, sl);
      *(float4*)(smem + P_WVR + lo) = gvr[s];
      *(float4*)(smem + P_WVI + lo) = gvi[s];
      *(float4*)(smem + P_WOR + lo) = gor[row * 64 + sl];
      *(float4*)(smem + P_WOI + lo) = goi[row * 64 + sl];
      *(float4*)(smem + P_AT + lo) = gat[s];
    }
    __syncthreads();
    // ---- V = mu * X*Wv (complex, DC imag zero), store transposed VT[d][t]
    {
      f32x4 vr[2][2] = {}, vi[2][2] = {};
#pragma unroll
      for (int ct = 0; ct < 2; ++ct)
#pragma unroll
        for (int kt = 0; kt < 2; ++kt) {
          int lo = swz128(32 * wc + ct * 16 + r, kt * 4 + g);
          f16x8 bwr = *(const f16x8*)(smem + P_WVR + lo);
          f16x8 bwi = *(const f16x8*)(smem + P_WVI + lo);
#pragma unroll
          for (int rt = 0; rt < 2; ++rt) {
            vr[rt][ct] = MFMA(axr[rt][kt], bwr, vr[rt][ct]);
            vr[rt][ct] = MFMA(axiN[rt][kt], bwi, vr[rt][ct]);
            vi[rt][ct] = MFMA(axr[rt][kt], bwi, vi[rt][ct]);
            vi[rt][ct] = MFMA(axi[rt][kt], bwr, vi[rt][ct]);
          }
        }
#pragma unroll
      for (int rt = 0; rt < 2; ++rt)
#pragma unroll
        for (int ct = 0; ct < 2; ++ct) {
          int drow = 32 * wc + ct * 16 + r;
          int t0 = 32 * wr + rt * 16 + g * 4;
          f16x4 pr, pi;
#pragma unroll
          for (int j = 0; j < 4; ++j) {
            pr[j] = (f16)(vr[rt][ct][j] * mu);
            pi[j] = (m == 0) ? (f16)0.f : (f16)(vi[rt][ct][j] * mu);
          }
          int lo = swzel(drow, t0);
          *(f16x4*)(smem + P_VTR + lo) = pr;
          *(f16x4*)(smem + P_VTI + lo) = pi;
        }
    }
    __syncthreads();
    // ---- Y = At * V ----
    {
      f16x8 aat[2][2];
#pragma unroll
      for (int rt = 0; rt < 2; ++rt)
#pragma unroll
        for (int kt = 0; kt < 2; ++kt)
          aat[rt][kt] = *(const f16x8*)(
              smem + P_AT + swz128(32 * wr + rt * 16 + r, kt * 4 + g));
      f32x4 yr[2][2] = {}, yi[2][2] = {};
#pragma unroll
      for (int ct = 0; ct < 2; ++ct)
#pragma unroll
        for (int kt = 0; kt < 2; ++kt) {
          int lo = swz128(32 * wc + ct * 16 + r, kt * 4 + g);
          f16x8 bvr = *(const f16x8*)(smem + P_VTR + lo);
          f16x8 bvi = *(const f16x8*)(smem + P_VTI + lo);
#pragma unroll
          for (int rt = 0; rt < 2; ++rt) {
            yr[rt][ct] = MFMA(aat[rt][kt], bvr, yr[rt][ct]);
            yi[rt][ct] = MFMA(aat[rt][kt], bvi, yi[rt][ct]);
          }
        }
#pragma unroll
      for (int rt = 0; rt < 2; ++rt)
#pragma unroll
        for (int ct = 0; ct < 2; ++ct)
#pragma unroll
          for (int j = 0; j < 4; ++j) {
            int row = 32 * wr + rt * 16 + g * 4 + j;
            int col = 32 * wc + ct * 16 + r;
            *(f16*)(smem + P_YR + swzel(row, col)) = (f16)yr[rt][ct][j];
            *(f16*)(smem + P_YI + swzel(row, col)) = (f16)yi[rt][ct][j];
          }
    }
    __syncthreads();
    // ---- F += Y * Wo (complex) ----
    {
      f16x8 ayr[2][2], ayi[2][2], ayiN[2][2];
#pragma unroll
      for (int rt = 0; rt < 2; ++rt)
#pragma unroll
        for (int kt = 0; kt < 2; ++kt) {
          int lo = swz128(32 * wr + rt * 16 + r, kt * 4 + g);
          ayr[rt][kt] = *(const f16x8*)(smem + P_YR + lo);
          ayi[rt][kt] = *(const f16x8*)(smem + P_YI + lo);
          ayiN[rt][kt] = -ayi[rt][kt];
        }
#pragma unroll
      for (int ct = 0; ct < 2; ++ct)
#pragma unroll
        for (int kt = 0; kt < 2; ++kt) {
          int lo = swz128(32 * wc + ct * 16 + r, kt * 4 + g);
          f16x8 bor = *(const f16x8*)(smem + P_WOR + lo);
          f16x8 boi = *(const f16x8*)(smem + P_WOI + lo);
#pragma unroll
          for (int rt = 0; rt < 2; ++rt) {
            fr[rt][ct] = MFMA(ayr[rt][kt], bor, fr[rt][ct]);
            fr[rt][ct] = MFMA(ayiN[rt][kt], boi, fr[rt][ct]);
            fi_[rt][ct] = MFMA(ayr[rt][kt], boi, fi_[rt][ct]);
            fi_[rt][ct] = MFMA(ayi[rt][kt], bor, fi_[rt][ct]);
          }
        }
    }
  }
#pragma unroll
  for (int rt = 0; rt < 2; ++rt)
#pragma unroll
    for (int ct = 0; ct < 2; ++ct)
#pragma unroll
      for (int j = 0; j < 4; ++j) {
        int s_ = 32 * wr + rt * 16 + g * 4 + j;
        int c_ = 32 * wc + ct * 16 + r;
        Ff[(((size_t)(b * 64 + s_)) * 64 + c_) * 256 + m] =
            make_float2(fr[rt][ct][j], fi_[rt][ct][j]);
      }
}

// ---------------- K5: inverse DFT -----------------------------------------
__global__ __launch_bounds__(256) void k_idft(const float2* __restrict__ Ff,
                                              float* __restrict__ out) {
  __shared__ float2 Fm[256];
  __shared__ float2 g[32][17];
  __shared__ float2 tw[32];
  int f = blockIdx.x;
  int tid = threadIdx.x;
  if (tid < 32) {
    float a = (2.0f * PI_F / 32.0f) * (float)tid;
    tw[tid] = make_float2(cosf(a), sinf(a));
  }
  Fm[tid] = Ff[(size_t)f * 256 + tid];
  __syncthreads();
  for (int o = tid; o < 512; o += 256) {
    int x = o >> 4, q = o & 15;
    float gr = 0.f, gi = 0.f;
#pragma unroll
    for (int p = 0; p < 16; ++p) {
      float2 a = Fm[p * 16 + q];
      float2 w = tw[(p * x) & 31];
      gr += a.x * w.x - a.y * w.y;
      gi += a.x * w.y + a.y * w.x;
    }
    g[x][q] = make_float2(gr, gi);
  }
  __syncthreads();
  int x = tid >> 3, j0 = (tid & 7) * 4;
  float4 r;
  float* rr = &r.x;
#pragma unroll
  for (int jj = 0; jj < 4; ++jj) {
    int j = j0 + jj;
    float acc = 0.f;
#pragma unroll
    for (int q = 0; q < 16; ++q) {
      float2 gv = g[x][q];
      float2 w = tw[(q * j) & 31];
      acc += gv.x * w.x - gv.y * w.y;
    }
    rr[jj] = acc * (1.0f / 1024.0f);
  }
  *(float4*)(out + (size_t)f * 1024 + x * 32 + j0) = r;
}

extern "C" void kernel_launch(void* const* d_in, const int* in_sizes, int n_in,
                              void* d_out, int out_size, void* d_ws,
                              size_t ws_size, hipStream_t stream) {
  const float* seq = (const float*)d_in[0];
  const float2* wq = (const float2*)d_in[1];
  const float2* wk = (const float2*)d_in[2];
  const float2* wv = (const float2*)d_in[3];
  const float2* wo = (const float2*)d_in[4];
  const float* w1 = (const float*)d_in[5];
  const float* b1 = (const float*)d_in[6];
  const float* w2 = (const float*)d_in[7];
  const float* b2 = (const float*)d_in[8];
  float* out = (float*)d_out;

  // ws layout (peak ~159.9 MB; proven ws_size >= 168,034,304 in R1)
  char* ws = (char*)d_ws;
  f16* Xr = (f16*)(ws + 0);                    //  4 MB
  f16* Xi = (f16*)(ws + 4194304);              //  4 MB
  float* scores = (float*)(ws + 8388608);      //  256 KB
  f16* At = (f16*)(ws + 8650752);              //  128 KB
  float2* Ff = (float2*)(ws + 8781824);        //  16 MB
  f16* Pqr = (f16*)(ws + 25559040);            //  16.77 MB each
  f16* Pqi = (f16*)(ws + 42336256);
  f16* Pkr = (f16*)(ws + 59113472);
  f16* Pki = (f16*)(ws + 75890688);
  f16* Pvr = (f16*)(ws + 92667904);
  f16* Pvi = (f16*)(ws + 109445120);
  f16* Por = (f16*)(ws + 126222336);
  f16* Poi = (f16*)(ws + 142999552);           // ends 159,776,768

  hipMemsetAsync(scores, 0, 262144, stream);
  k_dft<<<8192, 256, 0, stream>>>(seq, Xr, Xi);
  k_repack_all<<<8192, 256, 0, stream>>>(wq, wk, wv, wo, Pqr, Pqi, Pkr, Pki,
                                         Pvr, Pvi, Por, Poi);
  k_scores_m<<<dim3(32, 8, 2), 256, 0, stream>>>(Xr, Xi, Pqr, Pqi, Pkr, Pki,
                                                 scores);
  k_softmax<<<1024, 64, 0, stream>>>(scores, w1, b1, w2, b2, At);
  k_vpath_m<<<dim3(256, 2), 256, 0, stream>>>(Xr, Xi, Pvr, Pvi, Por, Poi, At,
                                              Ff);
  k_idft<<<8192, 256, 0, stream>>>(Ff, out);
}